// Round 1
// baseline (204.629 us; speedup 1.0000x reference)
//
#include <hip/hip_runtime.h>
#include <math.h>

// Precomputed-parameter layout in d_ws (floats):
//   P[0..3]    = cos(theta_q/2)          q=0..3
//   P[4..7]    = sin(theta_q/2)
//   P[8..263]  = At[k*16+j] = A[j][k] = sum_f w1[j][f]*S[k][f]   (A = W1 @ S^T)
//   P[264..279]= b1[16]
//   P[280..311]= w2[2][16] row-major
//   P[312..313]= b2[2]

__global__ void qc_prep(const float* __restrict__ uw, const float* __restrict__ w1,
                        const float* __restrict__ b1, const float* __restrict__ w2,
                        const float* __restrict__ b2, float* __restrict__ P) {
    int t = threadIdx.x;  // 256 threads, 1 block
    if (t < 4) {
        float th = 0.5f * uw[t * 2 + 0];   // phi (RZ) provably irrelevant to probs
        P[t]     = cosf(th);
        P[4 + t] = sinf(th);
    }
    // A^T entry: At[k][j] = sum_f w1[j][f] * S[k][f]
    int k = t >> 4, j = t & 15;
    float z0 = 1.0f - 2.0f * ((k >> 3) & 1);
    float z1 = 1.0f - 2.0f * ((k >> 2) & 1);
    float z2 = 1.0f - 2.0f * ((k >> 1) & 1);
    float z3 = 1.0f - 2.0f * ((k >> 0) & 1);
    float S[10] = { z0, z1, z2, z3,
                    z0 * z1, z0 * z2, z0 * z3, z1 * z2, z1 * z3, z2 * z3 };
    float acc = 0.0f;
#pragma unroll
    for (int f = 0; f < 10; ++f) acc += w1[j * 10 + f] * S[f];
    P[8 + k * 16 + j] = acc;

    if (t < 16) P[264 + t] = b1[t];
    if (t < 32) P[280 + t] = w2[t];
    if (t < 2)  P[312 + t] = b2[t];
}

__global__ __launch_bounds__(256) void qc_main(const float* __restrict__ x,
                                               const float* __restrict__ P,
                                               float* __restrict__ out, int batch) {
    int s = blockIdx.x * blockDim.x + threadIdx.x;
    if (s >= batch) return;

    const float4* xv = (const float4*)(x + (size_t)s * 16);
    float4 a0 = xv[0], a1 = xv[1], a2 = xv[2], a3 = xv[3];

    float y[16] = { a0.x, a0.y, a0.z, a0.w,
                    a1.x, a1.y, a1.z, a1.w,
                    a2.x, a2.y, a2.z, a2.w,
                    a3.x, a3.y, a3.z, a3.w };

    // 1/||x||^2 (RY rotations are orthogonal -> norm preserved; fold at the end)
    float ss = 0.0f;
#pragma unroll
    for (int i = 0; i < 16; ++i) ss = fmaf(y[i], y[i], ss);
    float r = 1.0f / ss;

    // 4 rounds of real 2x2 rotations (RY per qubit; qubit q = bit (3-q))
#pragma unroll
    for (int q = 0; q < 4; ++q) {
        const float cq = P[q], sq = P[4 + q];
        const int st = 8 >> q;
#pragma unroll
        for (int i = 0; i < 16; ++i) {
            if ((i & st) == 0) {
                float a = y[i], b = y[i + st];
                y[i]      = cq * a - sq * b;
                y[i + st] = fmaf(sq, a, cq * b);
            }
        }
    }

    // probs (unnormalized): p_k = y_k^2
    float p[16];
#pragma unroll
    for (int i = 0; i < 16; ++i) p[i] = y[i] * y[i];

    // t = A @ p  (A folded: W1 @ signs^T), wave-uniform P reads -> scalar loads
    float tacc[16];
#pragma unroll
    for (int j = 0; j < 16; ++j) tacc[j] = 0.0f;
#pragma unroll
    for (int k = 0; k < 16; ++k) {
        float pk = p[k];
        const float* Ak = P + 8 + k * 16;
#pragma unroll
        for (int j = 0; j < 16; ++j) tacc[j] = fmaf(Ak[j], pk, tacc[j]);
    }

    // h = relu(r*t + b1); out = W2 h + b2
    float o0 = P[312], o1 = P[313];
#pragma unroll
    for (int j = 0; j < 16; ++j) {
        float h = fmaf(tacc[j], r, P[264 + j]);
        h = fmaxf(h, 0.0f);
        o0 = fmaf(P[280 + j], h, o0);
        o1 = fmaf(P[296 + j], h, o1);
    }

    ((float2*)out)[s] = make_float2(o0, o1);
}

extern "C" void kernel_launch(void* const* d_in, const int* in_sizes, int n_in,
                              void* d_out, int out_size, void* d_ws, size_t ws_size,
                              hipStream_t stream) {
    const float* x  = (const float*)d_in[0];
    const float* uw = (const float*)d_in[1];
    const float* w1 = (const float*)d_in[2];
    const float* b1 = (const float*)d_in[3];
    const float* w2 = (const float*)d_in[4];
    const float* b2 = (const float*)d_in[5];
    float* out = (float*)d_out;
    float* P   = (float*)d_ws;   // needs 314 floats

    int batch = in_sizes[0] / 16;

    hipLaunchKernelGGL(qc_prep, dim3(1), dim3(256), 0, stream, uw, w1, b1, w2, b2, P);
    int blocks = (batch + 255) / 256;
    hipLaunchKernelGGL(qc_main, dim3(blocks), dim3(256), 0, stream, x, P, out, batch);
}